// Round 1
// baseline (71.749 us; speedup 1.0000x reference)
//
#include <hip/hip_runtime.h>

#define BB 8
#define TT 24
#define NN 4096   // C*C
#define HH 32

// ---------------- K1: row-normalize Flow rows; s[t]=sum(xn row); zero u bufs
__global__ __launch_bounds__(256) void k_norm(const float* __restrict__ Flow,
                                              float* __restrict__ xn,
                                              float* __restrict__ s,
                                              float* __restrict__ u /*3*B*T*H*/) {
    int row = blockIdx.x;                 // 0..B*T-1
    int tid = threadIdx.x;                // 0..255
    const float* x = Flow + (size_t)row * NN;
    float* xo = xn + (size_t)row * NN;

    float4 v[4];
    float ss = 0.f, sm = 0.f;
#pragma unroll
    for (int i = 0; i < 4; ++i) {
        v[i] = ((const float4*)x)[tid + i * 256];
        ss += v[i].x * v[i].x + v[i].y * v[i].y + v[i].z * v[i].z + v[i].w * v[i].w;
        sm += v[i].x + v[i].y + v[i].z + v[i].w;
    }
    // wave reduce (64 lanes)
#pragma unroll
    for (int off = 32; off > 0; off >>= 1) {
        ss += __shfl_down(ss, off);
        sm += __shfl_down(sm, off);
    }
    __shared__ float rss[4], rsm[4];
    int wave = tid >> 6, lane = tid & 63;
    if (lane == 0) { rss[wave] = ss; rsm[wave] = sm; }
    __syncthreads();
    float tss = rss[0] + rss[1] + rss[2] + rss[3];
    float tsm = rsm[0] + rsm[1] + rsm[2] + rsm[3];
    float rn = 1.0f / fmaxf(sqrtf(tss), 1e-12f);
#pragma unroll
    for (int i = 0; i < 4; ++i) {
        v[i].x *= rn; v[i].y *= rn; v[i].z *= rn; v[i].w *= rn;
        ((float4*)xo)[tid + i * 256] = v[i];
    }
    if (tid == 0) s[row] = tsm * rn;
    int gid = row * 256 + tid;
    if (gid < 3 * BB * TT * HH) u[gid] = 0.f;
}

// ---------------- K2: dinv[b][j] = deg>0 ? rsqrt(deg) : 0 ; deg = 1 + sum_t xn[t][j]*s[t]
__global__ __launch_bounds__(256) void k_dinv(const float* __restrict__ xn,
                                              const float* __restrict__ s,
                                              float* __restrict__ dinv) {
    int b = blockIdx.y;
    int j = blockIdx.x * 256 + threadIdx.x;
    const float* xb = xn + (size_t)b * TT * NN;
    const float* sb = s + b * TT;
    float acc = 1.0f;
#pragma unroll
    for (int t = 0; t < TT; ++t) acc += xb[t * NN + j] * sb[t];
    dinv[b * NN + j] = (acc > 0.f) ? rsqrtf(acc) : 0.f;
}

// ---------------- KA: z = dinv .* (x @ W); u += per-chunk partial of xn @ z (atomics)
__global__ __launch_bounds__(256) void k_layerA(const float* __restrict__ x,
                                                const float* __restrict__ W,
                                                const float* __restrict__ xn,
                                                const float* __restrict__ dinv,
                                                float* __restrict__ z,
                                                float* __restrict__ u) {
    int b = blockIdx.y;
    int j0 = blockIdx.x * 128;
    int tid = threadIdx.x;

    __shared__ float Ws[32][32];
    __shared__ float xs[128][33];
    __shared__ float zs[128][33];
    __shared__ float xns[24][128];

    for (int i = tid; i < 1024; i += 256) Ws[i >> 5][i & 31] = W[i];
    const float* xb = x + ((size_t)b * NN + j0) * HH;
    for (int i = tid; i < 4096; i += 256) xs[i >> 5][i & 31] = xb[i];
    const float* xnb = xn + (size_t)b * TT * NN + j0;
    for (int i = tid; i < 24 * 128; i += 256) xns[i >> 7][i & 127] = xnb[(i >> 7) * NN + (i & 127)];
    __syncthreads();

    int r = tid >> 1;
    int h0 = (tid & 1) * 16;
    float di = dinv[b * NN + j0 + r];
    float zr[16];
#pragma unroll
    for (int hh = 0; hh < 16; ++hh) {
        float acc = 0.f;
#pragma unroll
        for (int e = 0; e < 32; ++e) acc += xs[r][e] * Ws[e][h0 + hh];
        zr[hh] = di * acc;
        zs[r][h0 + hh] = zr[hh];
    }
    float* zb = z + ((size_t)b * NN + j0 + r) * HH + h0;
#pragma unroll
    for (int q = 0; q < 4; ++q)
        ((float4*)zb)[q] = make_float4(zr[4 * q], zr[4 * q + 1], zr[4 * q + 2], zr[4 * q + 3]);
    __syncthreads();

    // u partials: 768 (t,h) pairs, 3 per thread
#pragma unroll
    for (int k = 0; k < 3; ++k) {
        int p = tid + k * 256;
        int t = p >> 5, h = p & 31;
        float acc = 0.f;
#pragma unroll 8
        for (int rr = 0; rr < 128; ++rr) acc += xns[t][rr] * zs[rr][h];
        atomicAdd(&u[(b * TT + t) * HH + h], acc);
    }
}

// ---------------- KB: out = relu(dinv .* (xn^T u + z) + bias)
__global__ __launch_bounds__(256) void k_layerB(const float* __restrict__ z,
                                                const float* __restrict__ xn,
                                                const float* __restrict__ u,
                                                const float* __restrict__ dinv,
                                                const float* __restrict__ bias,
                                                float* __restrict__ out) {
    int b = blockIdx.y;
    int j0 = blockIdx.x * 128;
    int tid = threadIdx.x;

    __shared__ float us[24][32];
    __shared__ float xns[24][128];
    __shared__ float bs[32];

    for (int i = tid; i < 768; i += 256) us[i >> 5][i & 31] = u[b * TT * HH + i];
    if (tid < 32) bs[tid] = bias[tid];
    const float* xnb = xn + (size_t)b * TT * NN + j0;
    for (int i = tid; i < 24 * 128; i += 256) xns[i >> 7][i & 127] = xnb[(i >> 7) * NN + (i & 127)];
    __syncthreads();

    int r = tid >> 1;
    int h0 = (tid & 1) * 16;
    float di = dinv[b * NN + j0 + r];
    const float* zrow = z + ((size_t)b * NN + j0 + r) * HH + h0;
    float* orow = out + ((size_t)b * NN + j0 + r) * HH + h0;

    float4 zv[4];
#pragma unroll
    for (int q = 0; q < 4; ++q) zv[q] = ((const float4*)zrow)[q];
    float zreg[16];
#pragma unroll
    for (int q = 0; q < 4; ++q) {
        zreg[4 * q] = zv[q].x; zreg[4 * q + 1] = zv[q].y;
        zreg[4 * q + 2] = zv[q].z; zreg[4 * q + 3] = zv[q].w;
    }
    float o[16];
#pragma unroll
    for (int hh = 0; hh < 16; ++hh) {
        int h = h0 + hh;
        float acc = 0.f;
#pragma unroll
        for (int t = 0; t < 24; ++t) acc += xns[t][r] * us[t][h];
        float val = di * (acc + zreg[hh]) + bs[h];
        o[hh] = fmaxf(val, 0.f);
    }
#pragma unroll
    for (int q = 0; q < 4; ++q)
        ((float4*)orow)[q] = make_float4(o[4 * q], o[4 * q + 1], o[4 * q + 2], o[4 * q + 3]);
}

extern "C" void kernel_launch(void* const* d_in, const int* in_sizes, int n_in,
                              void* d_out, int out_size, void* d_ws, size_t ws_size,
                              hipStream_t stream) {
    const float* Flow = (const float*)d_in[0];
    const float* Edge = (const float*)d_in[1];
    const float* W0 = (const float*)d_in[2];
    const float* b0 = (const float*)d_in[3];
    const float* W1 = (const float*)d_in[4];
    const float* b1 = (const float*)d_in[5];
    const float* W2 = (const float*)d_in[6];
    const float* b2 = (const float*)d_in[7];
    float* out = (float*)d_out;

    float* ws = (float*)d_ws;
    float* xn   = ws;                                  // B*T*N
    float* s    = xn + (size_t)BB * TT * NN;           // B*T
    float* dinv = s + BB * TT;                         // B*N
    float* z    = dinv + (size_t)BB * NN;              // B*N*H
    float* u    = z + (size_t)BB * NN * HH;            // 3*B*T*H
    float* x1   = u + 3 * BB * TT * HH;                // B*N*H
    float* x2   = x1 + (size_t)BB * NN * HH;           // B*N*H

    k_norm<<<dim3(BB * TT), 256, 0, stream>>>(Flow, xn, s, u);
    k_dinv<<<dim3(16, BB), 256, 0, stream>>>(xn, s, dinv);

    k_layerA<<<dim3(32, BB), 256, 0, stream>>>(Edge, W0, xn, dinv, z, u);
    k_layerB<<<dim3(32, BB), 256, 0, stream>>>(z, xn, u, dinv, b0, x1);

    k_layerA<<<dim3(32, BB), 256, 0, stream>>>(x1, W1, xn, dinv, z, u + BB * TT * HH);
    k_layerB<<<dim3(32, BB), 256, 0, stream>>>(z, xn, u + BB * TT * HH, dinv, b1, x2);

    k_layerA<<<dim3(32, BB), 256, 0, stream>>>(x2, W2, xn, dinv, z, u + 2 * BB * TT * HH);
    k_layerB<<<dim3(32, BB), 256, 0, stream>>>(z, xn, u + 2 * BB * TT * HH, dinv, b2, out);
}

// Round 2
// 60.548 us; speedup vs baseline: 1.1850x; 1.1850x over previous
//
#include <hip/hip_runtime.h>

#define BB 8
#define TT 24
#define NN 4096   // C*C
#define HH 32

// ---------------- K1: row-normalize Flow rows; s[t]=sum(xn row); zero u bufs
__global__ __launch_bounds__(256) void k_norm(const float* __restrict__ Flow,
                                              float* __restrict__ xn,
                                              float* __restrict__ s,
                                              float* __restrict__ u /*3*B*T*H*/) {
    int row = blockIdx.x;                 // 0..B*T-1
    int tid = threadIdx.x;                // 0..255
    const float* x = Flow + (size_t)row * NN;
    float* xo = xn + (size_t)row * NN;

    float4 v[4];
    float ss = 0.f, sm = 0.f;
#pragma unroll
    for (int i = 0; i < 4; ++i) {
        v[i] = ((const float4*)x)[tid + i * 256];
        ss += v[i].x * v[i].x + v[i].y * v[i].y + v[i].z * v[i].z + v[i].w * v[i].w;
        sm += v[i].x + v[i].y + v[i].z + v[i].w;
    }
    // wave reduce (64 lanes)
#pragma unroll
    for (int off = 32; off > 0; off >>= 1) {
        ss += __shfl_down(ss, off);
        sm += __shfl_down(sm, off);
    }
    __shared__ float rss[4], rsm[4];
    int wave = tid >> 6, lane = tid & 63;
    if (lane == 0) { rss[wave] = ss; rsm[wave] = sm; }
    __syncthreads();
    float tss = rss[0] + rss[1] + rss[2] + rss[3];
    float tsm = rsm[0] + rsm[1] + rsm[2] + rsm[3];
    float rn = 1.0f / fmaxf(sqrtf(tss), 1e-12f);
#pragma unroll
    for (int i = 0; i < 4; ++i) {
        v[i].x *= rn; v[i].y *= rn; v[i].z *= rn; v[i].w *= rn;
        ((float4*)xo)[tid + i * 256] = v[i];
    }
    if (tid == 0) s[row] = tsm * rn;
    int gid = row * 256 + tid;
    if (gid < 3 * BB * TT * HH) u[gid] = 0.f;
}

// ---------------- K2: fused dinv + layerA(0):
// dinv[j] = rsqrt(1 + sum_t xn[t][j]*s[t]); z = dinv.*(Edge@W0); u0 += xn@z partials
__global__ __launch_bounds__(256) void k_dinvA(const float* __restrict__ Edge,
                                               const float* __restrict__ W,
                                               const float* __restrict__ xn,
                                               const float* __restrict__ s,
                                               float* __restrict__ dinv,
                                               float* __restrict__ z,
                                               float* __restrict__ u) {
    int b = blockIdx.y;
    int j0 = blockIdx.x * 128;
    int tid = threadIdx.x;

    __shared__ float Ws[32][32];
    __shared__ float xs[128][33];
    __shared__ float zs[128][33];
    __shared__ float xns[24][128];
    __shared__ float ss[24];

    if (tid < 24) ss[tid] = s[b * TT + tid];
    for (int i = tid; i < 1024; i += 256) Ws[i >> 5][i & 31] = W[i];
    const float* xb = Edge + ((size_t)b * NN + j0) * HH;
    for (int i = tid; i < 4096; i += 256) xs[i >> 5][i & 31] = xb[i];
    const float* xnb = xn + (size_t)b * TT * NN + j0;
    for (int i = tid; i < 24 * 128; i += 256) xns[i >> 7][i & 127] = xnb[(i >> 7) * NN + (i & 127)];
    __syncthreads();

    int r = tid >> 1;
    int h0 = (tid & 1) * 16;
    float deg = 1.0f;
#pragma unroll
    for (int t = 0; t < 24; ++t) deg += xns[t][r] * ss[t];
    float di = (deg > 0.f) ? rsqrtf(deg) : 0.f;
    if ((tid & 1) == 0) dinv[b * NN + j0 + r] = di;

    float zr[16];
#pragma unroll
    for (int hh = 0; hh < 16; ++hh) {
        float acc = 0.f;
#pragma unroll
        for (int e = 0; e < 32; ++e) acc += xs[r][e] * Ws[e][h0 + hh];
        zr[hh] = di * acc;
        zs[r][h0 + hh] = zr[hh];
    }
    float* zb = z + ((size_t)b * NN + j0 + r) * HH + h0;
#pragma unroll
    for (int q = 0; q < 4; ++q)
        ((float4*)zb)[q] = make_float4(zr[4 * q], zr[4 * q + 1], zr[4 * q + 2], zr[4 * q + 3]);
    __syncthreads();

    // u partials: 768 (t,h) pairs, 3 per thread
#pragma unroll
    for (int k = 0; k < 3; ++k) {
        int p = tid + k * 256;
        int t = p >> 5, h = p & 31;
        float acc = 0.f;
#pragma unroll 8
        for (int rr = 0; rr < 128; ++rr) acc += xns[t][rr] * zs[rr][h];
        atomicAdd(&u[(b * TT + t) * HH + h], acc);
    }
}

// ---------------- K3/K4: fused layerB(l) + layerA(l+1):
// xrow = relu(dinv.*(xn^T u_in + z_in) + bias); z_out = dinv.*(xrow@W); u_out += xn@z_out
__global__ __launch_bounds__(256) void k_fusedBA(const float* __restrict__ z_in,
                                                 const float* __restrict__ xn,
                                                 const float* __restrict__ u_in,
                                                 const float* __restrict__ dinv,
                                                 const float* __restrict__ bias,
                                                 const float* __restrict__ W,
                                                 float* __restrict__ z_out,
                                                 float* __restrict__ u_out) {
    int b = blockIdx.y;
    int j0 = blockIdx.x * 128;
    int tid = threadIdx.x;

    __shared__ float us[24][32];
    __shared__ float xns[24][128];
    __shared__ float Ws[32][32];
    __shared__ float xs[128][33];
    __shared__ float zs[128][33];
    __shared__ float bs[32];

    for (int i = tid; i < 768; i += 256) us[i >> 5][i & 31] = u_in[b * TT * HH + i];
    if (tid < 32) bs[tid] = bias[tid];
    for (int i = tid; i < 1024; i += 256) Ws[i >> 5][i & 31] = W[i];
    const float* xnb = xn + (size_t)b * TT * NN + j0;
    for (int i = tid; i < 24 * 128; i += 256) xns[i >> 7][i & 127] = xnb[(i >> 7) * NN + (i & 127)];
    __syncthreads();

    int r = tid >> 1;
    int h0 = (tid & 1) * 16;
    float di = dinv[b * NN + j0 + r];
    const float* zrow = z_in + ((size_t)b * NN + j0 + r) * HH + h0;

    float4 zv[4];
#pragma unroll
    for (int q = 0; q < 4; ++q) zv[q] = ((const float4*)zrow)[q];
    float zreg[16];
#pragma unroll
    for (int q = 0; q < 4; ++q) {
        zreg[4 * q] = zv[q].x; zreg[4 * q + 1] = zv[q].y;
        zreg[4 * q + 2] = zv[q].z; zreg[4 * q + 3] = zv[q].w;
    }
    // B-phase: x_{l+1} row half in registers -> xs
#pragma unroll
    for (int hh = 0; hh < 16; ++hh) {
        int h = h0 + hh;
        float acc = 0.f;
#pragma unroll
        for (int t = 0; t < 24; ++t) acc += xns[t][r] * us[t][h];
        xs[r][h] = fmaxf(di * (acc + zreg[hh]) + bs[h], 0.f);
    }
    // pair lane (tid^1) wrote the other half of xs[r][*]; same wave64 -> program
    // order + compiler lgkmcnt ordering make it visible without __syncthreads.
    // A-phase: z_out = dinv .* (xrow @ W)
    float zr[16];
#pragma unroll
    for (int hh = 0; hh < 16; ++hh) {
        float acc = 0.f;
#pragma unroll
        for (int e = 0; e < 32; ++e) acc += xs[r][e] * Ws[e][h0 + hh];
        zr[hh] = di * acc;
        zs[r][h0 + hh] = zr[hh];
    }
    float* zb = z_out + ((size_t)b * NN + j0 + r) * HH + h0;
#pragma unroll
    for (int q = 0; q < 4; ++q)
        ((float4*)zb)[q] = make_float4(zr[4 * q], zr[4 * q + 1], zr[4 * q + 2], zr[4 * q + 3]);
    __syncthreads();

#pragma unroll
    for (int k = 0; k < 3; ++k) {
        int p = tid + k * 256;
        int t = p >> 5, h = p & 31;
        float acc = 0.f;
#pragma unroll 8
        for (int rr = 0; rr < 128; ++rr) acc += xns[t][rr] * zs[rr][h];
        atomicAdd(&u_out[(b * TT + t) * HH + h], acc);
    }
}

// ---------------- K5: out = relu(dinv .* (xn^T u + z) + bias)
__global__ __launch_bounds__(256) void k_layerB(const float* __restrict__ z,
                                                const float* __restrict__ xn,
                                                const float* __restrict__ u,
                                                const float* __restrict__ dinv,
                                                const float* __restrict__ bias,
                                                float* __restrict__ out) {
    int b = blockIdx.y;
    int j0 = blockIdx.x * 128;
    int tid = threadIdx.x;

    __shared__ float us[24][32];
    __shared__ float xns[24][128];
    __shared__ float bs[32];

    for (int i = tid; i < 768; i += 256) us[i >> 5][i & 31] = u[b * TT * HH + i];
    if (tid < 32) bs[tid] = bias[tid];
    const float* xnb = xn + (size_t)b * TT * NN + j0;
    for (int i = tid; i < 24 * 128; i += 256) xns[i >> 7][i & 127] = xnb[(i >> 7) * NN + (i & 127)];
    __syncthreads();

    int r = tid >> 1;
    int h0 = (tid & 1) * 16;
    float di = dinv[b * NN + j0 + r];
    const float* zrow = z + ((size_t)b * NN + j0 + r) * HH + h0;
    float* orow = out + ((size_t)b * NN + j0 + r) * HH + h0;

    float4 zv[4];
#pragma unroll
    for (int q = 0; q < 4; ++q) zv[q] = ((const float4*)zrow)[q];
    float zreg[16];
#pragma unroll
    for (int q = 0; q < 4; ++q) {
        zreg[4 * q] = zv[q].x; zreg[4 * q + 1] = zv[q].y;
        zreg[4 * q + 2] = zv[q].z; zreg[4 * q + 3] = zv[q].w;
    }
    float o[16];
#pragma unroll
    for (int hh = 0; hh < 16; ++hh) {
        int h = h0 + hh;
        float acc = 0.f;
#pragma unroll
        for (int t = 0; t < 24; ++t) acc += xns[t][r] * us[t][h];
        float val = di * (acc + zreg[hh]) + bs[h];
        o[hh] = fmaxf(val, 0.f);
    }
#pragma unroll
    for (int q = 0; q < 4; ++q)
        ((float4*)orow)[q] = make_float4(o[4 * q], o[4 * q + 1], o[4 * q + 2], o[4 * q + 3]);
}

extern "C" void kernel_launch(void* const* d_in, const int* in_sizes, int n_in,
                              void* d_out, int out_size, void* d_ws, size_t ws_size,
                              hipStream_t stream) {
    const float* Flow = (const float*)d_in[0];
    const float* Edge = (const float*)d_in[1];
    const float* W0 = (const float*)d_in[2];
    const float* b0 = (const float*)d_in[3];
    const float* W1 = (const float*)d_in[4];
    const float* b1 = (const float*)d_in[5];
    const float* W2 = (const float*)d_in[6];
    const float* b2 = (const float*)d_in[7];
    float* out = (float*)d_out;

    float* ws = (float*)d_ws;
    float* xn   = ws;                                  // B*T*N
    float* s    = xn + (size_t)BB * TT * NN;           // B*T
    float* dinv = s + BB * TT;                         // B*N
    float* zA   = dinv + (size_t)BB * NN;              // B*N*H
    float* zB   = zA + (size_t)BB * NN * HH;           // B*N*H
    float* u    = zB + (size_t)BB * NN * HH;           // 3*B*T*H
    float* u0 = u, *u1 = u + BB * TT * HH, *u2 = u + 2 * BB * TT * HH;

    k_norm<<<dim3(BB * TT), 256, 0, stream>>>(Flow, xn, s, u);
    k_dinvA<<<dim3(32, BB), 256, 0, stream>>>(Edge, W0, xn, s, dinv, zA, u0);
    k_fusedBA<<<dim3(32, BB), 256, 0, stream>>>(zA, xn, u0, dinv, b0, W1, zB, u1);
    k_fusedBA<<<dim3(32, BB), 256, 0, stream>>>(zB, xn, u1, dinv, b1, W2, zA, u2);
    k_layerB<<<dim3(32, BB), 256, 0, stream>>>(zA, xn, u2, dinv, b2, out);
}